// Round 3
// baseline (383.359 us; speedup 1.0000x reference)
//
#include <hip/hip_runtime.h>
#include <hip/hip_bf16.h>

typedef unsigned short u16;
typedef __bf16 bf16x8 __attribute__((ext_vector_type(8)));
typedef float f32x4 __attribute__((ext_vector_type(4)));
typedef u16 u16x8 __attribute__((ext_vector_type(8)));

__device__ __forceinline__ u16 f2bf(float f) {
    __bf16 h = (__bf16)f;                 // RNE
    return __builtin_bit_cast(unsigned short, h);
}

__device__ __forceinline__ void gl_lds16(const u16* g, u16* l) {
    __builtin_amdgcn_global_load_lds(
        (const __attribute__((address_space(1))) void*)g,
        (__attribute__((address_space(3))) void*)l, 16, 0, 0);
}

// Explicitly drained barrier: vmcnt(0) (stage writes visible) + lgkmcnt(0)
// (ds_reads complete) before s_barrier. Never rely on implicit drain.
__device__ __forceinline__ void hard_barrier() {
    asm volatile("s_waitcnt vmcnt(0) lgkmcnt(0)" ::: "memory");
    __builtin_amdgcn_sched_barrier(0);
    __syncthreads();
}

// ---------------------------------------------------------------------------
// Fused prep kernel — ONE launch replaces quant + border + pad.
//   blocks [0,256):    quant for o = bid
//   blocks [256,4352): pad/transpose; pbid = bid-256 -> (img, cihi, z);
//                      z==3 threads 16..243 also zero the 228 halo cells.
// Outputs:
//   Wp[mt][kc36][kseg8][ol128][c8]  (conv A-tile image, 16 KB contiguous/chunk)
//   Xp[img][cihi32][58][58][8]      (padded NHWC8 bf16)
//   alpha[256]
// (Byte-identical to the round-2 passing version.)
// ---------------------------------------------------------------------------
__global__ __launch_bounds__(256) void prep_kernel(
        const float* __restrict__ x, const float* __restrict__ w,
        u16* __restrict__ xp, u16* __restrict__ wp,
        float* __restrict__ alpha) {
    __shared__ double red[4];
    __shared__ double red2[4];
    __shared__ int    redc[4];

    int bid = blockIdx.x;
    int t = threadIdx.x;

    if (bid < 256) {
        // ---------------- quant path: one block per output channel o ------
        int o = bid;
        const float* wo = w + (size_t)o * 2304;
        float v[9];
        double asum = 0.0;
        #pragma unroll
        for (int i = 0; i < 9; ++i) { v[i] = wo[t * 9 + i]; asum += fabs((double)v[i]); }
        #pragma unroll
        for (int off = 32; off > 0; off >>= 1) asum += __shfl_down(asum, off, 64);
        int wv = t >> 6, lane = t & 63;
        if (lane == 0) red[wv] = asum;
        __syncthreads();
        double delta = 0.7 * ((red[0] + red[1] + red[2] + red[3]) / 2304.0);

        int mt = o >> 7, ol = o & 127;
        int ks = (t >> 3) & 7, c = t & 7;
        double msum = 0.0; int cnt = 0;
        #pragma unroll
        for (int i = 0; i < 9; ++i) {
            double f = (double)v[i];
            float tv = 0.f;
            if (f > delta) tv = 1.f;
            else if (f < -delta) tv = -1.f;
            if (tv != 0.f) { msum += fabs(f); cnt++; }
            int kc = i * 4 + (t >> 6);
            wp[((((size_t)mt * 36 + kc) * 8 + ks) * 128 + ol) * 8 + c] = f2bf(tv);
        }
        #pragma unroll
        for (int off = 32; off > 0; off >>= 1) {
            msum += __shfl_down(msum, off, 64);
            cnt  += __shfl_down(cnt,  off, 64);
        }
        if (lane == 0) { red2[wv] = msum; redc[wv] = cnt; }
        __syncthreads();
        if (t == 0) {
            double ms = red2[0] + red2[1] + red2[2] + red2[3];
            int cn = redc[0] + redc[1] + redc[2] + redc[3];
            alpha[o] = (float)(ms / (double)(cn > 0 ? cn : 1));
        }
        return;
    }

    // ---------------- pad path ----------------------------------------------
    int pbid = bid - 256;
    int img  = pbid & 31;
    int cihi = (pbid >> 5) & 31;
    int z    = pbid >> 10;

    if (z == 3 && t >= 16) {
        // border: zero the 58x58 halo (228 cells) for this (img, cihi)
        int bt = t - 16;
        if (bt < 228) {
            int hp, wl;
            if (bt < 58)       { hp = 0;            wl = bt; }
            else if (bt < 116) { hp = 57;           wl = bt - 58; }
            else if (bt < 172) { hp = bt - 116 + 1; wl = 0; }
            else               { hp = bt - 172 + 1; wl = 57; }
            u16x8 zv = {};
            *(u16x8*)(xp + (((size_t)(img * 32 + cihi) * 58 + hp) * 58 + wl) * 8) = zv;
        }
        return;
    }

    int slot = z * 256 + t;           // z<3: slot<768; z==3,t<16: slot 768..783
    if (slot >= 784) return;
    int p = slot * 4;                 // flat h*56+w, 56%4==0 -> same h
    int h = p / 56, wq = p - h * 56;
    const float* xb = x + ((size_t)(img * 256 + cihi * 8)) * 3136 + p;
    f32x4 v[8];
    #pragma unroll
    for (int j = 0; j < 8; ++j) v[j] = *(const f32x4*)(xb + (size_t)j * 3136);
    u16* ob = xp + (((size_t)(img * 32 + cihi) * 58 + (h + 1)) * 58 + (wq + 1)) * 8;
    #pragma unroll
    for (int k = 0; k < 4; ++k) {
        u16x8 ov;
        #pragma unroll
        for (int j = 0; j < 8; ++j) ov[j] = f2bf(v[j][k]);
        *(u16x8*)(ob + k * 8) = ov;
    }
}

// ---------------------------------------------------------------------------
// Kernel 3: implicit GEMM, now 2-PHASE (T3-minimum recipe): double-buffered
// LDS (2 x 16 KB per operand = 64 KB total), stage of chunk kc+1 issued
// BEFORE compute of chunk kc, ONE vmcnt(0)+barrier per chunk.
// Race safety: reads of buf[cur] are register-complete before the barrier
// (lgkmcnt drain in hard_barrier); writes to buf[cur^1] are drained by the
// same vmcnt(0); flip after barrier. MFMA/fragment/epilogue unchanged.
// ---------------------------------------------------------------------------
__global__ __launch_bounds__(256) void conv_gemm(
        const u16* __restrict__ Wp, const u16* __restrict__ Xp,
        const float* __restrict__ alpha, float* __restrict__ out) {
    __shared__ u16 lsA[2][8 * 128 * 8];   // 2 x 16 KB: [kseg][o_row][8ch]
    __shared__ u16 lsB[2][8 * 128 * 8];   // 2 x 16 KB: [kseg][sp_row][8ch]

    // XCD swizzle: bid&7 = xcd owns a contiguous nt range (B-tile L2 reuse).
    // 784 % 8 == 0 -> bijective (ERRATA #11 safe).
    int bid = blockIdx.x;
    int xcd = bid & 7, idx = bid >> 3;
    int mt = idx & 1;
    unsigned nt = (unsigned)(xcd * 98 + (idx >> 1));
    int o_base = mt * 128;
    unsigned sp_base = nt * 128u;

    int t = threadIdx.x;
    int lane = t & 63, wave = t >> 6;
    int wm = (wave >> 1) * 64, wn = (wave & 1) * 64;

    // A staging: chunk kc's image = Wp + mt*294912 + kc*8192, 16 KB contiguous
    const u16* aTile = Wp + (size_t)mt * 294912;

    unsigned sp0 = sp_base + (unsigned)lane;
    unsigned sp1 = sp0 + 64u;
    unsigned img0 = sp0 / 3136u, rem0 = sp0 - img0 * 3136u;
    unsigned oh0 = rem0 / 56u,   ow0 = rem0 - oh0 * 56u;
    unsigned img1 = sp1 / 3136u, rem1 = sp1 - img1 * 3136u;
    unsigned oh1 = rem1 / 56u,   ow1 = rem1 - oh1 * 56u;
    const u16* bB0 = Xp + ((size_t)(img0 * 32) * 58 + oh0) * 58 * 8 + ow0 * 8;
    const u16* bB1 = Xp + ((size_t)(img1 * 32) * 58 + oh1) * 58 * 8 + ow1 * 8;

    int s0 = wave * 2, s1 = s0 + 1;

    f32x4 acc[4][4] = {};
    int row16 = lane & 15, quad = lane >> 4;

    // stage chunk kc into buffer buf (8 async gl_lds16 per wave)
    auto stage = [&](int kc, int buf) {
        int f  = kc >> 2;
        int kh = f / 3, kw = f - kh * 3;
        int ci8 = (kc & 3) * 8;
        unsigned bhw = (unsigned)kh * 464u + (unsigned)kw * 8u;
        unsigned bo0 = (unsigned)(ci8 + s0) * 26912u + bhw;
        unsigned bo1 = (unsigned)(ci8 + s1) * 26912u + bhw;
        const u16* aC = aTile + kc * 8192;
        #pragma unroll
        for (int q = 0; q < 4; ++q) {
            int seg = wave * 4 + q;                  // 16 segs of 512 u16
            gl_lds16(aC + seg * 512 + lane * 8, &lsA[buf][seg * 512]);
        }
        gl_lds16(bB0 + bo0, &lsB[buf][s0 * 1024]);
        gl_lds16(bB1 + bo0, &lsB[buf][s0 * 1024 + 512]);
        gl_lds16(bB0 + bo1, &lsB[buf][s1 * 1024]);
        gl_lds16(bB1 + bo1, &lsB[buf][s1 * 1024 + 512]);
    };

    // prologue: fill buffer 0 with chunk 0
    stage(0, 0);
    hard_barrier();

    int cur = 0;
    for (int kc = 0; kc < 36; ++kc) {
        if (kc + 1 < 36) stage(kc + 1, cur ^ 1);   // async, flies under compute

        const u16* cA = lsA[cur];
        const u16* cB = lsB[cur];
        #pragma unroll
        for (int kk = 0; kk < 2; ++kk) {
            int ks = kk * 4 + quad;
            bf16x8 af[4], bfr[4];
            #pragma unroll
            for (int i = 0; i < 4; ++i)
                af[i] = *(const bf16x8*)&cA[(ks * 128 + wm + i * 16 + row16) * 8];
            #pragma unroll
            for (int j = 0; j < 4; ++j)
                bfr[j] = *(const bf16x8*)&cB[(ks * 128 + wn + j * 16 + row16) * 8];
            #pragma unroll
            for (int i = 0; i < 4; ++i)
                #pragma unroll
                for (int j = 0; j < 4; ++j)
                    acc[i][j] = __builtin_amdgcn_mfma_f32_16x16x32_bf16(
                                    af[i], bfr[j], acc[i][j], 0, 0, 0);
        }

        if (kc + 1 < 36) {
            hard_barrier();   // drain stage (cur^1) + all reads of cur done
            cur ^= 1;
        }
    }

    // epilogue: C/D layout col=lane&15 (sp), row=quad*4+reg (o)
    int col = lane & 15;
    float al[4][4];
    #pragma unroll
    for (int i = 0; i < 4; ++i)
        #pragma unroll
        for (int rg = 0; rg < 4; ++rg)
            al[i][rg] = alpha[o_base + wm + i * 16 + quad * 4 + rg];

    #pragma unroll
    for (int j = 0; j < 4; ++j) {
        unsigned sp = sp_base + (unsigned)(wn + j * 16 + col);
        unsigned img = sp / 3136u;
        unsigned spi = sp - img * 3136u;
        float* ob = out + (size_t)img * 256 * 3136 + spi;
        #pragma unroll
        for (int i = 0; i < 4; ++i) {
            int o = o_base + wm + i * 16 + quad * 4;
            #pragma unroll
            for (int rg = 0; rg < 4; ++rg)
                ob[(size_t)(o + rg) * 3136] = acc[i][j][rg] * al[i][rg];
        }
    }
}

// ---------------------------------------------------------------------------
extern "C" void kernel_launch(void* const* d_in, const int* in_sizes, int n_in,
                              void* d_out, int out_size, void* d_ws, size_t ws_size,
                              hipStream_t stream) {
    const float* x = (const float*)d_in[0];
    const float* w = (const float*)d_in[1];
    float* out = (float*)d_out;

    char* ws = (char*)d_ws;
    // xp: 32*32*58*58*8 bf16 = 55,115,776 B
    u16*   xp    = (u16*)ws;
    u16*   wp    = (u16*)(ws + 55115776);           // 2*36*8*128*8 bf16 = 1,179,648 B
    float* alpha = (float*)(ws + 55115776 + 1179648);

    prep_kernel<<<4352, 256, 0, stream>>>(x, w, xp, wp, alpha);
    conv_gemm<<<784 * 2, 256, 0, stream>>>(wp, xp, alpha, out);
}

// Round 5
// 356.874 us; speedup vs baseline: 1.0742x; 1.0742x over previous
//
#include <hip/hip_runtime.h>
#include <hip/hip_bf16.h>

typedef unsigned short u16;
typedef __bf16 bf16x8 __attribute__((ext_vector_type(8)));
typedef float f32x4 __attribute__((ext_vector_type(4)));
typedef u16 u16x8 __attribute__((ext_vector_type(8)));

__device__ __forceinline__ u16 f2bf(float f) {
    __bf16 h = (__bf16)f;                 // RNE
    return __builtin_bit_cast(unsigned short, h);
}

__device__ __forceinline__ void gl_lds16(const u16* g, u16* l) {
    __builtin_amdgcn_global_load_lds(
        (const __attribute__((address_space(1))) void*)g,
        (__attribute__((address_space(3))) void*)l, 16, 0, 0);
}

// Explicitly drained barrier: vmcnt(0) (stage writes visible) + lgkmcnt(0)
// (ds_reads complete) before s_barrier. Never rely on implicit drain.
__device__ __forceinline__ void hard_barrier() {
    asm volatile("s_waitcnt vmcnt(0) lgkmcnt(0)" ::: "memory");
    __builtin_amdgcn_sched_barrier(0);
    __syncthreads();
}

// ---------------------------------------------------------------------------
// Fused prep kernel — ONE launch: quant (blocks 0..255) + pad/border.
// Byte-identical to the round-2/3 passing version (control for attribution).
// Outputs:
//   Wp[mt][kc36][kseg8][ol128][c8]  (conv A-tile image, 16 KB contiguous/chunk)
//   Xp[img][cihi32][58][58][8]      (padded NHWC8 bf16)
//   alpha[256]
// ---------------------------------------------------------------------------
__global__ __launch_bounds__(256) void prep_kernel(
        const float* __restrict__ x, const float* __restrict__ w,
        u16* __restrict__ xp, u16* __restrict__ wp,
        float* __restrict__ alpha) {
    __shared__ double red[4];
    __shared__ double red2[4];
    __shared__ int    redc[4];

    int bid = blockIdx.x;
    int t = threadIdx.x;

    if (bid < 256) {
        // ---------------- quant path: one block per output channel o ------
        int o = bid;
        const float* wo = w + (size_t)o * 2304;
        float v[9];
        double asum = 0.0;
        #pragma unroll
        for (int i = 0; i < 9; ++i) { v[i] = wo[t * 9 + i]; asum += fabs((double)v[i]); }
        #pragma unroll
        for (int off = 32; off > 0; off >>= 1) asum += __shfl_down(asum, off, 64);
        int wv = t >> 6, lane = t & 63;
        if (lane == 0) red[wv] = asum;
        __syncthreads();
        double delta = 0.7 * ((red[0] + red[1] + red[2] + red[3]) / 2304.0);

        int mt = o >> 7, ol = o & 127;
        int ks = (t >> 3) & 7, c = t & 7;
        double msum = 0.0; int cnt = 0;
        #pragma unroll
        for (int i = 0; i < 9; ++i) {
            double f = (double)v[i];
            float tv = 0.f;
            if (f > delta) tv = 1.f;
            else if (f < -delta) tv = -1.f;
            if (tv != 0.f) { msum += fabs(f); cnt++; }
            int kc = i * 4 + (t >> 6);
            wp[((((size_t)mt * 36 + kc) * 8 + ks) * 128 + ol) * 8 + c] = f2bf(tv);
        }
        #pragma unroll
        for (int off = 32; off > 0; off >>= 1) {
            msum += __shfl_down(msum, off, 64);
            cnt  += __shfl_down(cnt,  off, 64);
        }
        if (lane == 0) { red2[wv] = msum; redc[wv] = cnt; }
        __syncthreads();
        if (t == 0) {
            double ms = red2[0] + red2[1] + red2[2] + red2[3];
            int cn = redc[0] + redc[1] + redc[2] + redc[3];
            alpha[o] = (float)(ms / (double)(cn > 0 ? cn : 1));
        }
        return;
    }

    // ---------------- pad path ----------------------------------------------
    int pbid = bid - 256;
    int img  = pbid & 31;
    int cihi = (pbid >> 5) & 31;
    int z    = pbid >> 10;

    if (z == 3 && t >= 16) {
        // border: zero the 58x58 halo (228 cells) for this (img, cihi)
        int bt = t - 16;
        if (bt < 228) {
            int hp, wl;
            if (bt < 58)       { hp = 0;            wl = bt; }
            else if (bt < 116) { hp = 57;           wl = bt - 58; }
            else if (bt < 172) { hp = bt - 116 + 1; wl = 0; }
            else               { hp = bt - 172 + 1; wl = 57; }
            u16x8 zv = {};
            *(u16x8*)(xp + (((size_t)(img * 32 + cihi) * 58 + hp) * 58 + wl) * 8) = zv;
        }
        return;
    }

    int slot = z * 256 + t;           // z<3: slot<768; z==3,t<16: slot 768..783
    if (slot >= 784) return;
    int p = slot * 4;                 // flat h*56+w, 56%4==0 -> same h
    int h = p / 56, wq = p - h * 56;
    const float* xb = x + ((size_t)(img * 256 + cihi * 8)) * 3136 + p;
    f32x4 v[8];
    #pragma unroll
    for (int j = 0; j < 8; ++j) v[j] = *(const f32x4*)(xb + (size_t)j * 3136);
    u16* ob = xp + (((size_t)(img * 32 + cihi) * 58 + (h + 1)) * 58 + (wq + 1)) * 8;
    #pragma unroll
    for (int k = 0; k < 4; ++k) {
        u16x8 ov;
        #pragma unroll
        for (int j = 0; j < 8; ++j) ov[j] = f2bf(v[j][k]);
        *(u16x8*)(ob + k * 8) = ov;
    }
}

// ---------------------------------------------------------------------------
// Kernel 3: implicit GEMM — EXACT revert to the round-2 1-phase structure
// (163 µs measured; the 2-phase dbuf graft regressed to 204 µs, m99/m132
// confirmed). Split into two launches by mt (output-channel half) purely so
// each dispatch is ~83 µs < prep, making prep visible in the next top-5.
// Per launch: bid in [0,784), nt = (bid&7)*98 + (bid>>3) — bijective.
// ---------------------------------------------------------------------------
__global__ __launch_bounds__(256) void conv_gemm(
        const u16* __restrict__ Wp, const u16* __restrict__ Xp,
        const float* __restrict__ alpha, float* __restrict__ out,
        int mt) {
    __shared__ u16 lsA[8 * 128 * 8];   // 16 KB: [kseg][o_row][8ch]
    __shared__ u16 lsB[8 * 128 * 8];   // 16 KB: [kseg][sp_row][8ch]

    int bid = blockIdx.x;
    int xcd = bid & 7, idx = bid >> 3;          // idx in [0,98)
    unsigned nt = (unsigned)(xcd * 98 + idx);   // bijective, 784%8==0
    int o_base = mt * 128;
    unsigned sp_base = nt * 128u;

    int t = threadIdx.x;
    int lane = t & 63, wave = t >> 6;
    int wm = (wave >> 1) * 64, wn = (wave & 1) * 64;

    // A staging: chunk kc's image = Wp + mt*294912 + kc*8192, 16 KB contiguous
    const u16* aTile = Wp + (size_t)mt * 294912;

    unsigned sp0 = sp_base + (unsigned)lane;
    unsigned sp1 = sp0 + 64u;
    unsigned img0 = sp0 / 3136u, rem0 = sp0 - img0 * 3136u;
    unsigned oh0 = rem0 / 56u,   ow0 = rem0 - oh0 * 56u;
    unsigned img1 = sp1 / 3136u, rem1 = sp1 - img1 * 3136u;
    unsigned oh1 = rem1 / 56u,   ow1 = rem1 - oh1 * 56u;
    const u16* bB0 = Xp + ((size_t)(img0 * 32) * 58 + oh0) * 58 * 8 + ow0 * 8;
    const u16* bB1 = Xp + ((size_t)(img1 * 32) * 58 + oh1) * 58 * 8 + ow1 * 8;

    int s0 = wave * 2, s1 = s0 + 1;
    u16* dB00 = lsB + (s0 * 128) * 8;
    u16* dB01 = lsB + (s0 * 128 + 64) * 8;
    u16* dB10 = lsB + (s1 * 128) * 8;
    u16* dB11 = lsB + (s1 * 128 + 64) * 8;

    f32x4 acc[4][4] = {};
    int row16 = lane & 15, quad = lane >> 4;

    for (int kc = 0; kc < 36; ++kc) {
        int f  = kc >> 2;
        int kh = f / 3, kw = f - kh * 3;
        int ci8 = (kc & 3) * 8;
        unsigned bhw = (unsigned)kh * 464u + (unsigned)kw * 8u;
        unsigned bo0 = (unsigned)(ci8 + s0) * 26912u + bhw;
        unsigned bo1 = (unsigned)(ci8 + s1) * 26912u + bhw;
        const u16* aC = aTile + kc * 8192;

        #pragma unroll
        for (int q = 0; q < 4; ++q) {
            int seg = wave * 4 + q;                  // 16 segs of 512 u16
            gl_lds16(aC + seg * 512 + lane * 8, lsA + seg * 512);
        }
        gl_lds16(bB0 + bo0, dB00);
        gl_lds16(bB1 + bo0, dB01);
        gl_lds16(bB0 + bo1, dB10);
        gl_lds16(bB1 + bo1, dB11);

        hard_barrier();    // explicit vmcnt(0): staged data visible to all waves

        #pragma unroll
        for (int kk = 0; kk < 2; ++kk) {
            int ks = kk * 4 + quad;
            bf16x8 af[4], bfr[4];
            #pragma unroll
            for (int i = 0; i < 4; ++i)
                af[i] = *(const bf16x8*)&lsA[(ks * 128 + wm + i * 16 + row16) * 8];
            #pragma unroll
            for (int j = 0; j < 4; ++j)
                bfr[j] = *(const bf16x8*)&lsB[(ks * 128 + wn + j * 16 + row16) * 8];
            #pragma unroll
            for (int i = 0; i < 4; ++i)
                #pragma unroll
                for (int j = 0; j < 4; ++j)
                    acc[i][j] = __builtin_amdgcn_mfma_f32_16x16x32_bf16(
                                    af[i], bfr[j], acc[i][j], 0, 0, 0);
        }

        hard_barrier();    // all reads done before next chunk's staging
    }

    // epilogue: C/D layout col=lane&15 (sp), row=quad*4+reg (o)
    int col = lane & 15;
    float al[4][4];
    #pragma unroll
    for (int i = 0; i < 4; ++i)
        #pragma unroll
        for (int rg = 0; rg < 4; ++rg)
            al[i][rg] = alpha[o_base + wm + i * 16 + quad * 4 + rg];

    #pragma unroll
    for (int j = 0; j < 4; ++j) {
        unsigned sp = sp_base + (unsigned)(wn + j * 16 + col);
        unsigned img = sp / 3136u;
        unsigned spi = sp - img * 3136u;
        float* ob = out + (size_t)img * 256 * 3136 + spi;
        #pragma unroll
        for (int i = 0; i < 4; ++i) {
            int o = o_base + wm + i * 16 + quad * 4;
            #pragma unroll
            for (int rg = 0; rg < 4; ++rg)
                ob[(size_t)(o + rg) * 3136] = acc[i][j][rg] * al[i][rg];
        }
    }
}

// ---------------------------------------------------------------------------
extern "C" void kernel_launch(void* const* d_in, const int* in_sizes, int n_in,
                              void* d_out, int out_size, void* d_ws, size_t ws_size,
                              hipStream_t stream) {
    const float* x = (const float*)d_in[0];
    const float* w = (const float*)d_in[1];
    float* out = (float*)d_out;

    char* ws = (char*)d_ws;
    // xp: 32*32*58*58*8 bf16 = 55,115,776 B
    u16*   xp    = (u16*)ws;
    u16*   wp    = (u16*)(ws + 55115776);           // 2*36*8*128*8 bf16 = 1,179,648 B
    float* alpha = (float*)(ws + 55115776 + 1179648);

    prep_kernel<<<4352, 256, 0, stream>>>(x, w, xp, wp, alpha);
    conv_gemm<<<784, 256, 0, stream>>>(wp, xp, alpha, out, 0);
    conv_gemm<<<784, 256, 0, stream>>>(wp, xp, alpha, out, 1);
}

// Round 6
// 307.555 us; speedup vs baseline: 1.2465x; 1.1604x over previous
//
#include <hip/hip_runtime.h>
#include <hip/hip_bf16.h>

typedef unsigned short u16;
typedef __bf16 bf16x8 __attribute__((ext_vector_type(8)));
typedef float f32x4 __attribute__((ext_vector_type(4)));
typedef u16 u16x8 __attribute__((ext_vector_type(8)));

__device__ __forceinline__ u16 f2bf(float f) {
    __bf16 h = (__bf16)f;                 // RNE
    return __builtin_bit_cast(unsigned short, h);
}

__device__ __forceinline__ void gl_lds16(const u16* g, u16* l) {
    __builtin_amdgcn_global_load_lds(
        (const __attribute__((address_space(1))) void*)g,
        (__attribute__((address_space(3))) void*)l, 16, 0, 0);
}

// ---------------------------------------------------------------------------
// Fused prep kernel — ONE launch: quant (blocks 0..255) + pad/border.
// Byte-identical to the round-2/3/5 passing version (control).
// Outputs:
//   Wp[mt][kc36][kseg8][ol128][c8]  (conv A-tile image, 16 KB contiguous/chunk)
//   Xp[img][cihi32][58][58][8]      (padded NHWC8 bf16)
//   alpha[256]
// ---------------------------------------------------------------------------
__global__ __launch_bounds__(256) void prep_kernel(
        const float* __restrict__ x, const float* __restrict__ w,
        u16* __restrict__ xp, u16* __restrict__ wp,
        float* __restrict__ alpha) {
    __shared__ double red[4];
    __shared__ double red2[4];
    __shared__ int    redc[4];

    int bid = blockIdx.x;
    int t = threadIdx.x;

    if (bid < 256) {
        // ---------------- quant path: one block per output channel o ------
        int o = bid;
        const float* wo = w + (size_t)o * 2304;
        float v[9];
        double asum = 0.0;
        #pragma unroll
        for (int i = 0; i < 9; ++i) { v[i] = wo[t * 9 + i]; asum += fabs((double)v[i]); }
        #pragma unroll
        for (int off = 32; off > 0; off >>= 1) asum += __shfl_down(asum, off, 64);
        int wv = t >> 6, lane = t & 63;
        if (lane == 0) red[wv] = asum;
        __syncthreads();
        double delta = 0.7 * ((red[0] + red[1] + red[2] + red[3]) / 2304.0);

        int mt = o >> 7, ol = o & 127;
        int ks = (t >> 3) & 7, c = t & 7;
        double msum = 0.0; int cnt = 0;
        #pragma unroll
        for (int i = 0; i < 9; ++i) {
            double f = (double)v[i];
            float tv = 0.f;
            if (f > delta) tv = 1.f;
            else if (f < -delta) tv = -1.f;
            if (tv != 0.f) { msum += fabs(f); cnt++; }
            int kc = i * 4 + (t >> 6);
            wp[((((size_t)mt * 36 + kc) * 8 + ks) * 128 + ol) * 8 + c] = f2bf(tv);
        }
        #pragma unroll
        for (int off = 32; off > 0; off >>= 1) {
            msum += __shfl_down(msum, off, 64);
            cnt  += __shfl_down(cnt,  off, 64);
        }
        if (lane == 0) { red2[wv] = msum; redc[wv] = cnt; }
        __syncthreads();
        if (t == 0) {
            double ms = red2[0] + red2[1] + red2[2] + red2[3];
            int cn = redc[0] + redc[1] + redc[2] + redc[3];
            alpha[o] = (float)(ms / (double)(cn > 0 ? cn : 1));
        }
        return;
    }

    // ---------------- pad path ----------------------------------------------
    int pbid = bid - 256;
    int img  = pbid & 31;
    int cihi = (pbid >> 5) & 31;
    int z    = pbid >> 10;

    if (z == 3 && t >= 16) {
        // border: zero the 58x58 halo (228 cells) for this (img, cihi)
        int bt = t - 16;
        if (bt < 228) {
            int hp, wl;
            if (bt < 58)       { hp = 0;            wl = bt; }
            else if (bt < 116) { hp = 57;           wl = bt - 58; }
            else if (bt < 172) { hp = bt - 116 + 1; wl = 0; }
            else               { hp = bt - 172 + 1; wl = 57; }
            u16x8 zv = {};
            *(u16x8*)(xp + (((size_t)(img * 32 + cihi) * 58 + hp) * 58 + wl) * 8) = zv;
        }
        return;
    }

    int slot = z * 256 + t;           // z<3: slot<768; z==3,t<16: slot 768..783
    if (slot >= 784) return;
    int p = slot * 4;                 // flat h*56+w, 56%4==0 -> same h
    int h = p / 56, wq = p - h * 56;
    const float* xb = x + ((size_t)(img * 256 + cihi * 8)) * 3136 + p;
    f32x4 v[8];
    #pragma unroll
    for (int j = 0; j < 8; ++j) v[j] = *(const f32x4*)(xb + (size_t)j * 3136);
    u16* ob = xp + (((size_t)(img * 32 + cihi) * 58 + (h + 1)) * 58 + (wq + 1)) * 8;
    #pragma unroll
    for (int k = 0; k < 4; ++k) {
        u16x8 ov;
        #pragma unroll
        for (int j = 0; j < 8; ++j) ov[j] = f2bf(v[j][k]);
        *(u16x8*)(ob + k * 8) = ov;
    }
}

// ---------------------------------------------------------------------------
// Kernel 3: implicit GEMM, T3/T4 counted-vmcnt 2-deep pipeline.
//  - STATIC double buffers lsA0/lsA1, lsB0/lsB1 (rule #20: no runtime index).
//  - Raw s_barrier (never __syncthreads: it drains vmcnt(0) and kills overlap).
//  - Per half-iter: vmcnt(8) [oldest 8 = this buffer's loads, m135 in-order]
//    -> barrier -> 16 ds_read_b128 -> lgkmcnt(0) -> barrier (overwrite safe)
//    -> stage(kc+2, async, stays in flight across next barrier) -> 32 MFMA
//    wrapped in setprio(1) [T5: phase-split now exists].
//  - Single launch, interleaved mt (round-5 split showed 5x FETCH blowup:
//    46 -> 225 MB; co-resident mt pairs share B-tiles in L2).
// ---------------------------------------------------------------------------
#define STAGE_CHUNK(KC, LA, LB) do {                                        \
    int f_ = (KC) >> 2;                                                      \
    int kh_ = f_ / 3, kw_ = f_ - kh_ * 3;                                    \
    int ci8_ = ((KC) & 3) * 8;                                               \
    unsigned bhw_ = (unsigned)kh_ * 464u + (unsigned)kw_ * 8u;               \
    unsigned bo0_ = (unsigned)(ci8_ + s0) * 26912u + bhw_;                   \
    unsigned bo1_ = (unsigned)(ci8_ + s1) * 26912u + bhw_;                   \
    const u16* aC_ = aTile + (size_t)(KC) * 8192;                            \
    _Pragma("unroll")                                                        \
    for (int q_ = 0; q_ < 4; ++q_) {                                         \
        int seg_ = wave * 4 + q_;                                            \
        gl_lds16(aC_ + seg_ * 512 + lane * 8, (LA) + seg_ * 512);            \
    }                                                                        \
    gl_lds16(bB0 + bo0_, (LB) + s0 * 1024);                                  \
    gl_lds16(bB1 + bo0_, (LB) + s0 * 1024 + 512);                            \
    gl_lds16(bB0 + bo1_, (LB) + s1 * 1024);                                  \
    gl_lds16(bB1 + bo1_, (LB) + s1 * 1024 + 512);                            \
} while (0)

#define HALF_ITER(LA, LB, VMSTR, STAGE_KC, DO_STAGE) do {                    \
    asm volatile("s_waitcnt " VMSTR ::: "memory");                           \
    __builtin_amdgcn_sched_barrier(0);                                       \
    __builtin_amdgcn_s_barrier();                                            \
    __builtin_amdgcn_sched_barrier(0);                                       \
    bf16x8 af_[2][4], bf_[2][4];                                             \
    _Pragma("unroll")                                                        \
    for (int kk_ = 0; kk_ < 2; ++kk_) {                                      \
        int ks_ = kk_ * 4 + quad;                                            \
        _Pragma("unroll")                                                    \
        for (int i_ = 0; i_ < 4; ++i_)                                       \
            af_[kk_][i_] = *(const bf16x8*)&(LA)[(ks_ * 128 + wm + i_ * 16 + row16) * 8]; \
        _Pragma("unroll")                                                    \
        for (int j_ = 0; j_ < 4; ++j_)                                       \
            bf_[kk_][j_] = *(const bf16x8*)&(LB)[(ks_ * 128 + wn + j_ * 16 + row16) * 8]; \
    }                                                                        \
    __builtin_amdgcn_sched_barrier(0);                                       \
    asm volatile("s_waitcnt lgkmcnt(0)" ::: "memory");                       \
    __builtin_amdgcn_sched_barrier(0);                                       \
    __builtin_amdgcn_s_barrier();                                            \
    __builtin_amdgcn_sched_barrier(0);                                       \
    if (DO_STAGE) STAGE_CHUNK(STAGE_KC, LA, LB);                             \
    __builtin_amdgcn_s_setprio(1);                                           \
    _Pragma("unroll")                                                        \
    for (int kk_ = 0; kk_ < 2; ++kk_)                                        \
        _Pragma("unroll")                                                    \
        for (int i_ = 0; i_ < 4; ++i_)                                       \
            _Pragma("unroll")                                                \
            for (int j_ = 0; j_ < 4; ++j_)                                   \
                acc[i_][j_] = __builtin_amdgcn_mfma_f32_16x16x32_bf16(       \
                                af_[kk_][i_], bf_[kk_][j_], acc[i_][j_], 0, 0, 0); \
    __builtin_amdgcn_s_setprio(0);                                           \
} while (0)

__global__ __launch_bounds__(256, 2) void conv_gemm(
        const u16* __restrict__ Wp, const u16* __restrict__ Xp,
        const float* __restrict__ alpha, float* __restrict__ out) {
    __shared__ u16 lsA0[8 * 128 * 8];   // 16 KB each, 64 KB total
    __shared__ u16 lsA1[8 * 128 * 8];
    __shared__ u16 lsB0[8 * 128 * 8];
    __shared__ u16 lsB1[8 * 128 * 8];

    // XCD swizzle (round-2 mapping): 1568 % 8 == 0 -> bijective.
    int bid = blockIdx.x;
    int xcd = bid & 7, idx = bid >> 3;
    int mt = idx & 1;
    unsigned nt = (unsigned)(xcd * 98 + (idx >> 1));
    int o_base = mt * 128;
    unsigned sp_base = nt * 128u;

    int t = threadIdx.x;
    int lane = t & 63, wave = t >> 6;
    int wm = (wave >> 1) * 64, wn = (wave & 1) * 64;

    const u16* aTile = Wp + (size_t)mt * 294912;

    unsigned sp0 = sp_base + (unsigned)lane;
    unsigned sp1 = sp0 + 64u;
    unsigned img0 = sp0 / 3136u, rem0 = sp0 - img0 * 3136u;
    unsigned oh0 = rem0 / 56u,   ow0 = rem0 - oh0 * 56u;
    unsigned img1 = sp1 / 3136u, rem1 = sp1 - img1 * 3136u;
    unsigned oh1 = rem1 / 56u,   ow1 = rem1 - oh1 * 56u;
    const u16* bB0 = Xp + ((size_t)(img0 * 32) * 58 + oh0) * 58 * 8 + ow0 * 8;
    const u16* bB1 = Xp + ((size_t)(img1 * 32) * 58 + oh1) * 58 * 8 + ow1 * 8;

    int s0 = wave * 2, s1 = s0 + 1;

    f32x4 acc[4][4] = {};
    int row16 = lane & 15, quad = lane >> 4;

    // prologue: both buffers' stages in flight (16 loads/wave outstanding)
    STAGE_CHUNK(0, lsA0, lsB0);
    STAGE_CHUNK(1, lsA1, lsB1);

    // main loop: 17 iters processing chunks kc, kc+1; staging kc+2, kc+3.
    #pragma unroll 1
    for (int kc = 0; kc < 34; kc += 2) {
        HALF_ITER(lsA0, lsB0, "vmcnt(8)", kc + 2, true);
        HALF_ITER(lsA1, lsB1, "vmcnt(8)", kc + 3, true);
    }
    // tail: chunks 34 (buf0, staged at kc=32 iter) and 35 (buf1).
    HALF_ITER(lsA0, lsB0, "vmcnt(8)", 0, false);
    HALF_ITER(lsA1, lsB1, "vmcnt(0)", 0, false);

    // epilogue: C/D layout col=lane&15 (sp), row=quad*4+reg (o)
    int col = lane & 15;
    float al[4][4];
    #pragma unroll
    for (int i = 0; i < 4; ++i)
        #pragma unroll
        for (int rg = 0; rg < 4; ++rg)
            al[i][rg] = alpha[o_base + wm + i * 16 + quad * 4 + rg];

    #pragma unroll
    for (int j = 0; j < 4; ++j) {
        unsigned sp = sp_base + (unsigned)(wn + j * 16 + col);
        unsigned img = sp / 3136u;
        unsigned spi = sp - img * 3136u;
        float* ob = out + (size_t)img * 256 * 3136 + spi;
        #pragma unroll
        for (int i = 0; i < 4; ++i) {
            int o = o_base + wm + i * 16 + quad * 4;
            #pragma unroll
            for (int rg = 0; rg < 4; ++rg)
                ob[(size_t)(o + rg) * 3136] = acc[i][j][rg] * al[i][rg];
        }
    }
}

// ---------------------------------------------------------------------------
extern "C" void kernel_launch(void* const* d_in, const int* in_sizes, int n_in,
                              void* d_out, int out_size, void* d_ws, size_t ws_size,
                              hipStream_t stream) {
    const float* x = (const float*)d_in[0];
    const float* w = (const float*)d_in[1];
    float* out = (float*)d_out;

    char* ws = (char*)d_ws;
    // xp: 32*32*58*58*8 bf16 = 55,115,776 B
    u16*   xp    = (u16*)ws;
    u16*   wp    = (u16*)(ws + 55115776);           // 2*36*8*128*8 bf16 = 1,179,648 B
    float* alpha = (float*)(ws + 55115776 + 1179648);

    prep_kernel<<<4352, 256, 0, stream>>>(x, w, xp, wp, alpha);
    conv_gemm<<<784 * 2, 256, 0, stream>>>(wp, xp, alpha, out);
}